// Round 5
// baseline (197.909 us; speedup 1.0000x reference)
//
#include <hip/hip_runtime.h>

// out[n][p][m] = sum_c x[n][c][p] * rm[n][c][m]
// N=16, C=64, P=65536, M=128. Memory-bound: 256MB read + 512MB write -> floor ~122us.
// v5 = v4 (161.6us) + occupancy 16->24 waves/CU: rm staging unioned into the x
//      buffer (LDS 33KB -> 16.9KB) + __launch_bounds__(256,6).
//      Discriminates mixed-stream-HBM-ceiling (neutral) vs concurrency-bound (win).

#define NB   16
#define CDIM 64
#define PDIM 65536
#define MDIM 128
#define PT   128
#define BLOCKS_PER_N 64
#define TILES_PER_BLOCK 8
#define XS   132   // lds_x row stride (bf16); 64*132 = 8448 shorts = 16.9KB

typedef __attribute__((ext_vector_type(8))) short bf16x8;
typedef __attribute__((ext_vector_type(4))) float f32x4;

__device__ __forceinline__ unsigned short f2bf(float f) {
  union { float f; unsigned int u; } v; v.f = f;
  unsigned int u = v.u;
  u += 0x7fffu + ((u >> 16) & 1u);  // RNE
  return (unsigned short)(u >> 16);
}

// rm staging swizzle (verified): [m][64c] bf16, 16B-slot XOR. Max index 8191 < 8448.
__device__ __forceinline__ int swz(int row, int col) {
  int slot = (col >> 3) ^ (row & 7);
  return row * 64 + slot * 8 + (col & 7);
}

// x tile: [c][p], p XOR-swizzled by c-group -> conflict-free (2-way) gathers.
// XOR touches only p bits 4-5, so 4-elem (8B) write chunks stay contiguous.
__device__ __forceinline__ int xswz(int c, int p) {
  return c * XS + (p ^ (((c >> 3) & 3) << 4));
}

__global__ __launch_bounds__(256, 6) void nlsa_kernel(
    const float* __restrict__ x, const float* __restrict__ rm,
    float* __restrict__ out) {
  // Single buffer: rm staging (16KB) first, then x tiles (16.9KB). 6 blocks/CU.
  __shared__ unsigned short lds[CDIM * XS];

  const int t = threadIdx.x;
  const int b = blockIdx.x;
  const int n  = b >> 6;
  const int bt = b & 63;

  const float* xn   = x  + (size_t)n * CDIM * PDIM;
  const float* rmn  = rm + (size_t)n * CDIM * MDIM;
  float*       outn = out + (size_t)n * PDIM * MDIM;

  const int cst = t >> 5;          // 0..7
  const int pst = (t & 31) * 4;    // 0..124

  float4 r[8];
  {
    const float* src = xn + (size_t)(bt * PT + pst);
#pragma unroll
    for (int it = 0; it < 8; ++it)
      r[it] = *(const float4*)(src + (size_t)(cst + it * 8) * PDIM);
  }

  // ---- stage rm[n] -> lds as [m][c] bf16 (once per block)
  {
    const int m  = t & 127;
    const int cb = (t >> 7) * 4;
#pragma unroll
    for (int it = 0; it < 8; ++it) {
      const int c0 = cb + it * 8;
      ushort4 v;
      v.x = f2bf(rmn[(c0 + 0) * MDIM + m]);
      v.y = f2bf(rmn[(c0 + 1) * MDIM + m]);
      v.z = f2bf(rmn[(c0 + 2) * MDIM + m]);
      v.w = f2bf(rmn[(c0 + 3) * MDIM + m]);
      *(ushort4*)&lds[swz(m, c0)] = v;
    }
  }
  __syncthreads();

  const int w  = t >> 6;    // wave: m range [32w, 32w+32)
  const int l  = t & 63;
  const int lo = l & 15;
  const int g  = l >> 4;

  // A fragments (rm) in registers for the whole kernel
  bf16x8 a[2][2];
#pragma unroll
  for (int mt = 0; mt < 2; ++mt)
#pragma unroll
    for (int ks = 0; ks < 2; ++ks)
      a[mt][ks] = *(const bf16x8*)&lds[swz(w * 32 + mt * 16 + lo,
                                           ks * 32 + g * 8)];
  // Reads must have landed in registers before this wave passes the next
  // barrier (other waves then overwrite the unioned buffer with x tiles).
  asm volatile("s_waitcnt lgkmcnt(0)" ::: "memory");

  for (int k = 0; k < TILES_PER_BLOCK; ++k) {
    // barrier1: all waves done reading lds for tile k-1 / rm fragments.
    asm volatile("" ::: "memory");
    __builtin_amdgcn_s_barrier();
    asm volatile("" ::: "memory");

    // write staged tile into lds (compiler inserts counted vmcnt for r)
#pragma unroll
    for (int it = 0; it < 8; ++it) {
      ushort4 v;
      v.x = f2bf(r[it].x); v.y = f2bf(r[it].y);
      v.z = f2bf(r[it].z); v.w = f2bf(r[it].w);
      *(ushort4*)&lds[xswz(cst + it * 8, pst)] = v;
    }

    // prefetch tile k+1 into r (overlaps the compute phase below)
    if (k + 1 < TILES_PER_BLOCK) {
      const float* src = xn + (size_t)((bt + (k + 1) * BLOCKS_PER_N) * PT + pst);
#pragma unroll
      for (int it = 0; it < 8; ++it)
        r[it] = *(const float4*)(src + (size_t)(cst + it * 8) * PDIM);
    }

    // barrier2: lds writes visible; lgkm-only wait (store queue NOT drained)
    asm volatile("s_waitcnt lgkmcnt(0)" ::: "memory");
    __builtin_amdgcn_s_barrier();
    asm volatile("" ::: "memory");

    const int p_base = (bt + k * BLOCKS_PER_N) * PT;
#pragma unroll
    for (int pt_ = 0; pt_ < 8; ++pt_) {
      const int pl  = pt_ * 16 + lo;
      const int pls = pl ^ (g << 4);   // matches xswz for c-groups g and g+4
      bf16x8 b0, b1;
#pragma unroll
      for (int i = 0; i < 8; ++i) {
        b0[i] = (short)lds[(g * 8 + i) * XS + pls];
        b1[i] = (short)lds[(32 + g * 8 + i) * XS + pls];
      }
      f32x4 acc0 = {0.f, 0.f, 0.f, 0.f};
      f32x4 acc1 = {0.f, 0.f, 0.f, 0.f};
      acc0 = __builtin_amdgcn_mfma_f32_16x16x32_bf16(a[0][0], b0, acc0, 0, 0, 0);
      acc0 = __builtin_amdgcn_mfma_f32_16x16x32_bf16(a[0][1], b1, acc0, 0, 0, 0);
      acc1 = __builtin_amdgcn_mfma_f32_16x16x32_bf16(a[1][0], b0, acc1, 0, 0, 0);
      acc1 = __builtin_amdgcn_mfma_f32_16x16x32_bf16(a[1][1], b1, acc1, 0, 0, 0);

      float* dst = outn + (size_t)(p_base + pl) * MDIM + w * 32 + g * 4;
      *(f32x4*)(dst)      = acc0;   // m = 32w + 4g + {0..3}
      *(f32x4*)(dst + 16) = acc1;   // m = 32w + 16 + 4g + {0..3}
    }
  }
}

extern "C" void kernel_launch(void* const* d_in, const int* in_sizes, int n_in,
                              void* d_out, int out_size, void* d_ws, size_t ws_size,
                              hipStream_t stream) {
  const float* x  = (const float*)d_in[0];   // (N, C, H, W) fp32
  const float* rm = (const float*)d_in[1];   // (N, C, M) fp32
  float* out = (float*)d_out;                // (N, P, M) fp32
  nlsa_kernel<<<dim3(NB * BLOCKS_PER_N), dim3(256), 0, stream>>>(x, rm, out);
}